// Round 11
// baseline (179.012 us; speedup 1.0000x reference)
//
#include <hip/hip_runtime.h>
#include <hip/hip_bf16.h>
#include <cstdint>

// Problem constants: B=2, T=2048, D_IN=D_OUT=1024, H=16, DH=64
#define SEQ_T 2048
#define DMODEL 1024
#define NHEAD 16
#define DHEAD 64

typedef __attribute__((ext_vector_type(8))) __bf16 bf16x8;
typedef __attribute__((ext_vector_type(4))) float floatx4;
typedef __attribute__((ext_vector_type(16))) float floatx16;
typedef __attribute__((ext_vector_type(2))) unsigned uint32x2;

static __device__ __forceinline__ uint16_t f2bf(float f) {
    union { float f; uint32_t u; } v; v.f = f;
    uint32_t r = v.u + 0x7FFFu + ((v.u >> 16) & 1u);   // RNE
    return (uint16_t)(r >> 16);
}

static __device__ __forceinline__ uint32_t pack2bf(float a, float b) {
    // compiler fuses paired casts into v_cvt_pk_bf16_f32 (m240: faster than hand asm)
    union { __bf16 h[2]; uint32_t u; } p;
    p.h[0] = (__bf16)a; p.h[1] = (__bf16)b;
    return p.u;
}

// -------- merged fp32->bf16 converts: z<4 weight transpose, z==4 x --------
// W_q (z==0) pre-scaled by 0.125*log2(e): QK^T emits s*C directly, so the
// attention softmax is a single raw v_exp_f32 (__builtin_amdgcn_exp2f).
__global__ void mha_cvt(const float* __restrict__ x, uint16_t* __restrict__ xb,
                        const float* __restrict__ W0, const float* __restrict__ W1,
                        const float* __restrict__ W2, const float* __restrict__ W3,
                        uint16_t* __restrict__ T0, uint16_t* __restrict__ T1,
                        uint16_t* __restrict__ T2, uint16_t* __restrict__ T3) {
    if (blockIdx.z == 4) {
        int base = (blockIdx.y * 16 + blockIdx.x) * 256 + threadIdx.x;
#pragma unroll
        for (int i = 0; i < 16; ++i) {
            int idx = base + i * 65536;
            float4 f = ((const float4*)x)[idx];
            union { uint16_t u[4]; uint64_t v; } o;
            o.u[0] = f2bf(f.x); o.u[1] = f2bf(f.y); o.u[2] = f2bf(f.z); o.u[3] = f2bf(f.w);
            ((uint64_t*)xb)[idx] = o.v;
        }
        return;
    }
    const float* W; uint16_t* Tt; float sc;
    switch (blockIdx.z) {
        case 0: W = W0; Tt = T0; sc = 0.125f * 1.44269504089f; break;
        case 1: W = W1; Tt = T1; sc = 1.f; break;
        case 2: W = W2; Tt = T2; sc = 1.f; break;
        default: W = W3; Tt = T3; sc = 1.f; break;
    }
    __shared__ float tile[64][65];
    const int c  = threadIdx.x & 63;
    const int r0 = threadIdx.x >> 6;
    const int R0 = blockIdx.y * 64, C0 = blockIdx.x * 64;
#pragma unroll
    for (int rr = 0; rr < 16; ++rr) {
        int r = r0 + rr * 4;
        tile[r][c] = W[(size_t)(R0 + r) * DMODEL + C0 + c];
    }
    __syncthreads();
#pragma unroll
    for (int rr = 0; rr < 16; ++rr) {
        int r = r0 + rr * 4;
        Tt[(size_t)(C0 + r) * DMODEL + R0 + c] = f2bf(tile[c][r] * sc);
    }
}

// ------ bf16 MFMA GEMM, 64M x 128N tile, BK=64, B^T input, swizzled ------
// (R10/R12-proven shape; qkv grid 1536 = 6 blocks/CU @ 24 KB dynamic LDS.)
// Swizzle: row r slot q' holds source sub-chunk q'^(r&7) -> 2-way-only.
// MODE 0: bf16 row-major out. MODE 1: Vt[(b*1024+col)*2048+t] via LDS
// transpose reusing staging smem.
template<int MODE>
__device__ __forceinline__ void gemm_bk64_body(
    const uint16_t* __restrict__ A, const uint16_t* __restrict__ Bt,
    uint16_t* __restrict__ outB) {
    const int K = DMODEL, N = DMODEL;
    extern __shared__ char smem[];                  // 24576 B dynamic
    uint16_t* As = (uint16_t*)smem;                 // [64][64]  8 KB
    uint16_t* Bs = (uint16_t*)(smem + 8192);        // [128][64] 16 KB
    const int tid  = threadIdx.x;
    const int wave = tid >> 6;
    const int lane = tid & 63;
    const int m0 = blockIdx.y * 64;
    const int n0 = blockIdx.x * 128;
    const int lr   = lane & 15;
    const int quad = lane >> 4;

    floatx4 acc[4][2];
#pragma unroll
    for (int i = 0; i < 4; ++i)
#pragma unroll
        for (int j = 0; j < 2; ++j) acc[i][j] = (floatx4)0.0f;

    for (int k0 = 0; k0 < K; k0 += 64) {
#pragma unroll
        for (int i = 0; i < 2; ++i) {               // A: 512 chunks (16B)
            int c = i * 256 + tid;
            int r = c >> 3, s = (c & 7) ^ (r & 7);
            const uint16_t* g = A + (size_t)(m0 + r) * K + k0 + s * 8;
            __builtin_amdgcn_global_load_lds((const __attribute__((address_space(1))) void*)g,
                                             (__attribute__((address_space(3))) void*)(As + (size_t)c * 8), 16, 0, 0);
        }
#pragma unroll
        for (int i = 0; i < 4; ++i) {               // B: 1024 chunks
            int c = i * 256 + tid;
            int r = c >> 3, s = (c & 7) ^ (r & 7);
            const uint16_t* g = Bt + (size_t)(n0 + r) * K + k0 + s * 8;
            __builtin_amdgcn_global_load_lds((const __attribute__((address_space(1))) void*)g,
                                             (__attribute__((address_space(3))) void*)(Bs + (size_t)c * 8), 16, 0, 0);
        }
        __syncthreads();
#pragma unroll
        for (int ks = 0; ks < 2; ++ks) {            // two 32-wide k-halves
            bf16x8 af[4], bfr[2];
#pragma unroll
            for (int mi = 0; mi < 4; ++mi) {
                int row = mi * 16 + lr;
                af[mi] = *(const bf16x8*)&As[row * 64 + (((ks * 4 + quad) ^ (row & 7)) << 3)];
            }
#pragma unroll
            for (int ni = 0; ni < 2; ++ni) {
                int row = wave * 32 + ni * 16 + lr;
                bfr[ni] = *(const bf16x8*)&Bs[row * 64 + (((ks * 4 + quad) ^ (row & 7)) << 3)];
            }
#pragma unroll
            for (int mi = 0; mi < 4; ++mi)
#pragma unroll
                for (int ni = 0; ni < 2; ++ni)
                    acc[mi][ni] = __builtin_amdgcn_mfma_f32_16x16x32_bf16(af[mi], bfr[ni], acc[mi][ni], 0, 0, 0);
        }
        __syncthreads();
    }
    if constexpr (MODE == 1) {
        uint16_t* Ct = (uint16_t*)smem;             // [128][72], 18.4 KB
        const int bb = m0 >> 11, t0 = m0 & 2047;
#pragma unroll
        for (int mi = 0; mi < 4; ++mi)
#pragma unroll
            for (int ni = 0; ni < 2; ++ni) {
                int cl = wave * 32 + ni * 16 + lr;
                int tl = mi * 16 + quad * 4;
                int tls = tl ^ ((cl & 3) << 4);     // 2-way-only bank pattern
                union { uint16_t u[4]; uint64_t v8; } pk;
#pragma unroll
                for (int r = 0; r < 4; ++r) pk.u[r] = f2bf(acc[mi][ni][r]);
                *(uint64_t*)&Ct[cl * 72 + tls] = pk.v8;
            }
        __syncthreads();
#pragma unroll
        for (int k = 0; k < 4; ++k) {
            int c = k * 256 + tid;                  // 1024 chunks of 16B
            int cl = c >> 3, off = (c & 7) * 8;
            int offs = off ^ ((cl & 3) << 4);
            uint4 v = *(const uint4*)&Ct[cl * 72 + offs];
            *(uint4*)&outB[((size_t)(bb * 1024 + n0 + cl)) * 2048 + t0 + off] = v;
        }
    } else {
#pragma unroll
        for (int mi = 0; mi < 4; ++mi)
#pragma unroll
            for (int ni = 0; ni < 2; ++ni) {
                int col = n0 + wave * 32 + ni * 16 + lr;
#pragma unroll
                for (int r = 0; r < 4; ++r) {
                    int row = m0 + mi * 16 + quad * 4 + r;
                    outB[(size_t)row * N + col] = f2bf(acc[mi][ni][r]);
                }
            }
    }
}

__global__ __launch_bounds__(256) void mha_gemm_qkv(
    const uint16_t* __restrict__ A,
    const uint16_t* __restrict__ Wq, const uint16_t* __restrict__ Wk, const uint16_t* __restrict__ Wv,
    uint16_t* __restrict__ Q, uint16_t* __restrict__ K, uint16_t* __restrict__ Vt) {
    switch (blockIdx.z) {
        case 0:  gemm_bk64_body<0>(A, Wq, Q);  break;
        case 1:  gemm_bk64_body<0>(A, Wk, K);  break;
        default: gemm_bk64_body<1>(A, Wv, Vt); break;
    }
}

// ---- out-projection GEMM: 64M x 128N, BK=64, 512 thr / 8 waves ----
// (R14-best config: wave-tile 32x32, grid (8,64) = 2 blocks/CU x 8 waves
// = 16 waves/CU.)
__global__ __launch_bounds__(512) void mha_gemm_out(
    const uint16_t* __restrict__ A, const uint16_t* __restrict__ Wot,
    float* __restrict__ out, const float* __restrict__ bias) {
    const int K = DMODEL, N = DMODEL;
    extern __shared__ char smem[];                  // 24576 B dynamic
    uint16_t* As = (uint16_t*)smem;                 // [64][64]  8 KB
    uint16_t* Bs = (uint16_t*)(smem + 8192);        // [128][64] 16 KB
    const int tid  = threadIdx.x;
    const int wave = tid >> 6;
    const int lane = tid & 63;
    const int m0 = blockIdx.y * 64;
    const int n0 = blockIdx.x * 128;
    const int lr   = lane & 15;
    const int quad = lane >> 4;
    const int wm = wave >> 2, wn = wave & 3;        // 2m x 4n wave grid

    floatx4 acc[2][2];
#pragma unroll
    for (int i = 0; i < 2; ++i)
#pragma unroll
        for (int j = 0; j < 2; ++j) acc[i][j] = (floatx4)0.0f;

    for (int k0 = 0; k0 < K; k0 += 64) {
        {                                           // A: 512 chunks
            int c = tid;
            int r = c >> 3, s = (c & 7) ^ (r & 7);
            const uint16_t* g = A + (size_t)(m0 + r) * K + k0 + s * 8;
            __builtin_amdgcn_global_load_lds((const __attribute__((address_space(1))) void*)g,
                                             (__attribute__((address_space(3))) void*)(As + (size_t)c * 8), 16, 0, 0);
        }
#pragma unroll
        for (int i = 0; i < 2; ++i) {               // B: 1024 chunks
            int c = i * 512 + tid;
            int r = c >> 3, s = (c & 7) ^ (r & 7);
            const uint16_t* g = Wot + (size_t)(n0 + r) * K + k0 + s * 8;
            __builtin_amdgcn_global_load_lds((const __attribute__((address_space(1))) void*)g,
                                             (__attribute__((address_space(3))) void*)(Bs + (size_t)c * 8), 16, 0, 0);
        }
        __syncthreads();
#pragma unroll
        for (int ks = 0; ks < 2; ++ks) {
            bf16x8 af[2], bfr[2];
#pragma unroll
            for (int mi = 0; mi < 2; ++mi) {
                int row = wm * 32 + mi * 16 + lr;
                af[mi] = *(const bf16x8*)&As[row * 64 + (((ks * 4 + quad) ^ (row & 7)) << 3)];
            }
#pragma unroll
            for (int ni = 0; ni < 2; ++ni) {
                int row = wn * 32 + ni * 16 + lr;
                bfr[ni] = *(const bf16x8*)&Bs[row * 64 + (((ks * 4 + quad) ^ (row & 7)) << 3)];
            }
#pragma unroll
            for (int mi = 0; mi < 2; ++mi)
#pragma unroll
                for (int ni = 0; ni < 2; ++ni)
                    acc[mi][ni] = __builtin_amdgcn_mfma_f32_16x16x32_bf16(af[mi], bfr[ni], acc[mi][ni], 0, 0, 0);
        }
        __syncthreads();
    }
#pragma unroll
    for (int mi = 0; mi < 2; ++mi)
#pragma unroll
        for (int ni = 0; ni < 2; ++ni) {
            int col = n0 + wn * 32 + ni * 16 + lr;
            float bv = bias[col];
#pragma unroll
            for (int r = 0; r < 4; ++r) {
                int row = m0 + wm * 32 + mi * 16 + quad * 4 + r;
                out[(size_t)row * N + col] = acc[mi][ni][r] + bv;
            }
        }
}

// ---------------- MFMA flash attention (causal, fixed-base softmax) -------
// R11: split-kv. The sole surviving cross-round model: per-BLOCK DMA rate
// is capped ~4-6 B/cyc regardless of sync style (R10: counted-vmcnt null),
// occupancy (R1), or LDS traffic (R2); wall = per-block staged bytes /
// rate (R0-R10 all fit). So: halve per-block staged bytes AND keep 2
// barrier domains/CU. Each (h,p,b) pair-job splits into TWO blocks, each
// owning one 64-col half of every 128-kv supertile:
//   * grid (16 h, 8 p, 4 z=kvhB*2+b) = 512 = 2 blocks/CU. Per-block
//     staged = 17 iters x 16 KB = 272 KB (half of R3/R10).
//   * 512 thr, 8 waves = 4 qg(32 q-rows) x 2 kvq(32 kv-cols). q-tile 128,
//     pairs jH=15-p / jL=p; TH=jH+1, 17 iters. Per-wave iter = half of
//     R10's (1 strip): 4 QK MFMA + in-reg softmax + 4 PV MFMA.
//   * Fixed-base softmax => o,l additive ACROSS blocks: each block
//     writes f32 o-partial (no /l) + l-partial; mha_merge combines.
//     f32 partials (not bf16) to hold absmax; WRITE_SIZE ~33 MB is
//     intended (VGPR ~92 = no spill is the discriminator).
//   * LDS 65 KB: Ks[2][64x64] 16K + Vs[2][64x64] 16K + osc 32K dedicated
//     merge scratch + lbuf 1K -> 2 blocks/CU at 130 KB.
//   * Simple 2-buffer + __syncthreads (counted-vmcnt proven irrelevant).
__global__ __launch_bounds__(512, 2) void mha_attn_mfma(
    const uint16_t* __restrict__ Q, const uint16_t* __restrict__ K,
    const uint16_t* __restrict__ Vt, float* __restrict__ opart,
    float* __restrict__ lpart) {
    extern __shared__ char asmem[];
    uint16_t* Ks0 = (uint16_t*)asmem;              // [2][64*64] 16 KB [kv][d]
    uint16_t* Vs0 = (uint16_t*)(asmem + 16384);    // [2][64*64] 16 KB [d][kv]
    float*    osc = (float*)(asmem + 32768);       // [128][64] f32, 32 KB
    float*    lbuf = (float*)(asmem + 65536);      // 256 f32

    const int tid  = threadIdx.x;
    const int wave = tid >> 6;
    const int lane = tid & 63;
    const int l31  = lane & 31;
    const int hi   = lane >> 5;
    const int l7   = lane & 7;
    const int qg   = wave & 3;             // q-row group (32 rows, 4 groups)
    const int kvq  = wave >> 2;            // kv quarter within strip (32 cols)
    const int h    = blockIdx.x;           // head fastest -> XCD locality
    const int p    = blockIdx.y;           // 0..7
    const int kvhB = blockIdx.z >> 1;      // which 64-col half of supertiles
    const int b    = blockIdx.z & 1;
    const int jH = 15 - p, jL = p;         // paired 128-row q-tiles
    const int TH = jH + 1;                 // TH + TL = 17

    // staging: 1 K chunk + 1 V chunk per thread (512 thr = 64x64 tiles),
    // XOR source swizzle, linear LDS dest
    const uint16_t* kg;
    const uint16_t* vg;
    {
        int c = tid;                              // chunk 0..511 (16 B)
        int rk = c >> 3, ck = c & 7;              // K: 64 rows x 8 chunks
        kg = K + ((size_t)(b * SEQ_T) + kvhB * 64 + rk) * DMODEL + h * DHEAD + ((ck ^ (rk & 7)) * 8);
        int rv = c >> 3, cv = c & 7;              // V: 64 d-rows x 8 chunks
        vg = Vt + ((size_t)(b * 1024 + h * DHEAD + rv)) * 2048 + kvhB * 64 + ((cv ^ (rv & 7)) * 8);
    }

    int q0w = jH * 128 + qg * 32;          // this wave's q base
    bf16x8 qf[4];
    auto load_q = [&]() {
        const uint16_t* qb = Q + ((size_t)(b * SEQ_T) + q0w + l31) * DMODEL + h * DHEAD;
#pragma unroll
        for (int f = 0; f < 4; ++f)
            qf[f] = *(const bf16x8*)(qb + f * 16 + hi * 8);
    };
    load_q();

    floatx16 o[2];
#pragma unroll
    for (int dt = 0; dt < 2; ++dt) o[dt] = (floatx16)0.0f;
    float lac = 0.f;

    auto stage = [&](int kv0, int buf) {   // 2 global_load_lds per thread
        __builtin_amdgcn_global_load_lds(
            (const __attribute__((address_space(1))) void*)(kg + (size_t)kv0 * DMODEL),
            (__attribute__((address_space(3))) void*)(Ks0 + buf * 4096 + tid * 8), 16, 0, 0);
        __builtin_amdgcn_global_load_lds(
            (const __attribute__((address_space(1))) void*)(vg + kv0),
            (__attribute__((address_space(3))) void*)(Vs0 + buf * 4096 + tid * 8), 16, 0, 0);
    };
    auto kvof = [&](int t) { return (t < TH ? t : t - TH) * 128; };

    // own + partner-half value (lane l <-> l^32) summed
    auto halfsum = [&](float x) -> float {
#if __has_builtin(__builtin_amdgcn_permlane32_swap)
        uint32x2 r = __builtin_amdgcn_permlane32_swap(__float_as_uint(x), __float_as_uint(x), false, false);
        return __uint_as_float(r.x) + __uint_as_float(r.y);
#else
        return x + __shfl_xor(x, 32, 64);
#endif
    };

    // merge kvq=1 into kvq=0 via dedicated osc scratch (no DMA hazard),
    // then write f32 o-partial (no normalization) + l-partial to global.
    auto combine_store = [&]() {
        __syncthreads();
        float lt = halfsum(lac);
        if (kvq == 1) {
#pragma unroll
            for (int dt = 0; dt < 2; ++dt)
#pragma unroll
                for (int r = 0; r < 16; ++r) {
                    int row = (r & 3) + 8 * (r >> 2) + 4 * hi;
                    osc[(qg * 32 + row) * 64 + dt * 32 + l31] = o[dt][r];
                }
            if (lane < 32) lbuf[qg * 32 + lane] = lt;
        }
        __syncthreads();
        if (kvq == 0) {
            float* op = opart + (size_t)kvhB * (4096u * 1024u);
            if (lane < 32) {
                float ltot = lt + lbuf[qg * 32 + lane];
                lpart[((size_t)(kvhB * 2 + b) * SEQ_T + q0w + lane) * NHEAD + h] = ltot;
            }
#pragma unroll
            for (int dt = 0; dt < 2; ++dt)
#pragma unroll
                for (int r = 0; r < 16; ++r) {
                    int row = (r & 3) + 8 * (r >> 2) + 4 * hi;
                    float ov = o[dt][r] + osc[(qg * 32 + row) * 64 + dt * 32 + l31];
                    op[((size_t)(b * SEQ_T) + q0w + row) * DMODEL + h * DHEAD + dt * 32 + l31] = ov;
                }
        }
    };

    stage(kvof(0), 0);
    __syncthreads();

    for (int t = 0; t < 17; ++t) {
        const int cur = t & 1;
        const int kv0 = kvof(t);
        if (t + 1 < 17) stage(kvof(t + 1), (t + 1) & 1);
        const uint16_t* Kc = Ks0 + cur * 4096;
        const uint16_t* Vc = Vs0 + cur * 4096;
        const int kb = kv0 + kvhB * 64 + kvq * 32;
        // QK^T swapped: S^T[k][q] = mfma(K, Q); lane: q = l31, k by reg
        floatx16 s = (floatx16)0.0f;
        __builtin_amdgcn_s_setprio(1);
#pragma unroll
        for (int f = 0; f < 4; ++f) {
            bf16x8 kf = *(const bf16x8*)&Kc[(kvq * 32 + l31) * 64 + (((2 * f + hi) ^ l7) << 3)];
            s = __builtin_amdgcn_mfma_f32_32x32x16_bf16(kf, qf[f], s, 0, 0, 0);
        }
        __builtin_amdgcn_s_setprio(0);
        if (kb + 31 > q0w) {               // causal mask (covers overhang)
            int qr = q0w + l31;
#pragma unroll
            for (int r = 0; r < 16; ++r) {
                int k = kb + (r & 3) + 8 * (r >> 2) + 4 * hi;
                if (k > qr) s[r] = -3e38f;
            }
        }
        // p = exp2(s) (scale folded into W_q); l rides a VALU sum
        uint32_t d0[2], d1[2], d2[2], d3[2];
#pragma unroll
        for (int i = 0; i < 2; ++i) {
            float a, c2;
            a = __builtin_amdgcn_exp2f(s[2 * i]);      c2 = __builtin_amdgcn_exp2f(s[2 * i + 1]);
            lac += a + c2; d0[i] = pack2bf(a, c2);
            a = __builtin_amdgcn_exp2f(s[4 + 2 * i]);  c2 = __builtin_amdgcn_exp2f(s[4 + 2 * i + 1]);
            lac += a + c2; d1[i] = pack2bf(a, c2);
            a = __builtin_amdgcn_exp2f(s[8 + 2 * i]);  c2 = __builtin_amdgcn_exp2f(s[8 + 2 * i + 1]);
            lac += a + c2; d2[i] = pack2bf(a, c2);
            a = __builtin_amdgcn_exp2f(s[12 + 2 * i]); c2 = __builtin_amdgcn_exp2f(s[12 + 2 * i + 1]);
            lac += a + c2; d3[i] = pack2bf(a, c2);
        }
        // redistribute across lane halves -> PV A-frags (k contiguous)
        bf16x8 paf[2];
#if __has_builtin(__builtin_amdgcn_permlane32_swap)
        {
            uint32x2 r0 = __builtin_amdgcn_permlane32_swap(d0[0], d1[0], false, false);
            uint32x2 r1 = __builtin_amdgcn_permlane32_swap(d0[1], d1[1], false, false);
            union { uint32_t u[4]; bf16x8 v; } f0;
            f0.u[0] = r0.x; f0.u[1] = r1.x; f0.u[2] = r0.y; f0.u[3] = r1.y;
            paf[0] = f0.v;
            uint32x2 r2 = __builtin_amdgcn_permlane32_swap(d2[0], d3[0], false, false);
            uint32x2 r3 = __builtin_amdgcn_permlane32_swap(d2[1], d3[1], false, false);
            union { uint32_t u[4]; bf16x8 v; } f1;
            f1.u[0] = r2.x; f1.u[1] = r3.x; f1.u[2] = r2.y; f1.u[3] = r3.y;
            paf[1] = f1.v;
        }
#else
        {
            uint32_t s00 = __shfl_xor((int)d0[0], 32, 64), s01 = __shfl_xor((int)d0[1], 32, 64);
            uint32_t s10 = __shfl_xor((int)d1[0], 32, 64), s11 = __shfl_xor((int)d1[1], 32, 64);
            union { uint32_t u[4]; bf16x8 v; } f0;
            f0.u[0] = hi ? s10 : d0[0]; f0.u[1] = hi ? s11 : d0[1];
            f0.u[2] = hi ? d1[0] : s00; f0.u[3] = hi ? d1[1] : s01;
            paf[0] = f0.v;
            uint32_t s20 = __shfl_xor((int)d2[0], 32, 64), s21 = __shfl_xor((int)d2[1], 32, 64);
            uint32_t s30 = __shfl_xor((int)d3[0], 32, 64), s31 = __shfl_xor((int)d3[1], 32, 64);
            union { uint32_t u[4]; bf16x8 v; } f1;
            f1.u[0] = hi ? s30 : d2[0]; f1.u[1] = hi ? s31 : d2[1];
            f1.u[2] = hi ? d3[0] : s20; f1.u[3] = hi ? d3[1] : s21;
            paf[1] = f1.v;
        }
#endif
        // PV: O[q][d] += P x V  (A = in-reg P, B = V^T rows from LDS)
        __builtin_amdgcn_s_setprio(1);
#pragma unroll
        for (int f = 0; f < 2; ++f)
#pragma unroll
            for (int dt = 0; dt < 2; ++dt) {
                bf16x8 vf = *(const bf16x8*)&Vc[(dt * 32 + l31) * 64 + (((kvq * 4 + 2 * f + hi) ^ l7) << 3)];
                o[dt] = __builtin_amdgcn_mfma_f32_32x32x16_bf16(paf[f], vf, o[dt], 0, 0, 0);
            }
        __builtin_amdgcn_s_setprio(0);
        if (t == TH - 1) {                 // high q-tile done: write partials
            combine_store();
            q0w = jL * 128 + qg * 32;
            load_q();
#pragma unroll
            for (int dt = 0; dt < 2; ++dt) o[dt] = (floatx16)0.0f;
            lac = 0.f;
        }
        if (t + 1 < 17) __syncthreads();   // next buffer staged & landed
    }
    combine_store();                       // low q-tile partials
}

// ---- merge: ctx = (o0 + o1) / (l0 + l1), f32 -> bf16, elementwise ----
// 4096x1024 elems = 1,048,576 float4 chunks; 2048 blocks x 256 thr x 2.
__global__ __launch_bounds__(256) void mha_merge(
    const float* __restrict__ opart, const float* __restrict__ lpart,
    uint16_t* __restrict__ ctx) {
    const float* o0 = opart;
    const float* o1 = opart + (size_t)4096 * 1024;
    int base = blockIdx.x * 256 + threadIdx.x;
#pragma unroll
    for (int i = 0; i < 2; ++i) {
        int cidx = base + i * 524288;
        int row = cidx >> 8;               // 0..4095  (= b*2048 + q)
        int hh  = (cidx & 255) >> 4;       // head
        float l0 = lpart[(size_t)row * NHEAD + hh];
        float l1 = lpart[((size_t)4096 + row) * NHEAD + hh];
        float linv = 1.f / (l0 + l1);
        float4 a = ((const float4*)o0)[cidx];
        float4 c = ((const float4*)o1)[cidx];
        union { uint16_t u[4]; uint64_t v; } pk;
        pk.u[0] = f2bf((a.x + c.x) * linv);
        pk.u[1] = f2bf((a.y + c.y) * linv);
        pk.u[2] = f2bf((a.z + c.z) * linv);
        pk.u[3] = f2bf((a.w + c.w) * linv);
        ((uint64_t*)ctx)[cidx] = pk.v;
    }
}

extern "C" void kernel_launch(void* const* d_in, const int* in_sizes, int n_in,
                              void* d_out, int out_size, void* d_ws, size_t ws_size,
                              hipStream_t stream) {
    const float* x  = (const float*)d_in[0];
    const float* Wq = (const float*)d_in[1];
    const float* Wk = (const float*)d_in[2];
    const float* Wv = (const float*)d_in[3];
    const float* Wo = (const float*)d_in[4];
    const float* bo = (const float*)d_in[5];
    float* out = (float*)d_out;

    char* ws = (char*)d_ws;
    const size_t SZ_X = (size_t)4096 * DMODEL * 2;   // 8 MB
    const size_t SZ_W = (size_t)DMODEL * DMODEL * 2; // 2 MB
    size_t off = 0;
    uint16_t* xb  = (uint16_t*)(ws + off); off += SZ_X;
    uint16_t* wqt = (uint16_t*)(ws + off); off += SZ_W;
    uint16_t* wkt = (uint16_t*)(ws + off); off += SZ_W;
    uint16_t* wvt = (uint16_t*)(ws + off); off += SZ_W;
    uint16_t* wot = (uint16_t*)(ws + off); off += SZ_W;
    uint16_t* Qb  = (uint16_t*)(ws + off); off += SZ_X;
    uint16_t* Kb  = (uint16_t*)(ws + off); off += SZ_X;
    uint16_t* Vtb = (uint16_t*)(ws + off); off += SZ_X;  // per-head transposed V
    uint16_t* Cb  = (uint16_t*)(ws + off); off += SZ_X;
    float* opart  = (float*)(ws + off);    off += (size_t)2 * 4096 * 1024 * 4; // 32 MB
    float* lpart  = (float*)(ws + off);    off += (size_t)2 * 4096 * NHEAD * 4; // 512 KB
    (void)ws_size; (void)in_sizes; (void)n_in; (void)out_size;

    mha_cvt<<<dim3(16, 16, 5), 256, 0, stream>>>(x, xb, Wq, Wk, Wv, Wo, wqt, wkt, wvt, wot);
    mha_gemm_qkv<<<dim3(8, 64, 3), 256, 24576, stream>>>(xb, wqt, wkt, wvt, Qb, Kb, Vtb);
    mha_attn_mfma<<<dim3(NHEAD, 8, 4), 512, 66560, stream>>>(Qb, Kb, Vtb, opart, lpart);
    mha_merge<<<dim3(2048), 256, 0, stream>>>(opart, lpart, Cb);
    mha_gemm_out<<<dim3(8, 64), 512, 24576, stream>>>(Cb, wot, out, bo);
}

// Round 12
// 166.782 us; speedup vs baseline: 1.0733x; 1.0733x over previous
//
#include <hip/hip_runtime.h>
#include <hip/hip_bf16.h>
#include <cstdint>

// Problem constants: B=2, T=2048, D_IN=D_OUT=1024, H=16, DH=64
#define SEQ_T 2048
#define DMODEL 1024
#define NHEAD 16
#define DHEAD 64

typedef __attribute__((ext_vector_type(8))) __bf16 bf16x8;
typedef __attribute__((ext_vector_type(4))) float floatx4;
typedef __attribute__((ext_vector_type(16))) float floatx16;
typedef __attribute__((ext_vector_type(2))) unsigned uint32x2;

static __device__ __forceinline__ uint16_t f2bf(float f) {
    union { float f; uint32_t u; } v; v.f = f;
    uint32_t r = v.u + 0x7FFFu + ((v.u >> 16) & 1u);   // RNE
    return (uint16_t)(r >> 16);
}

static __device__ __forceinline__ uint32_t pack2bf(float a, float b) {
    // compiler fuses paired casts into v_cvt_pk_bf16_f32 (m240: faster than hand asm)
    union { __bf16 h[2]; uint32_t u; } p;
    p.h[0] = (__bf16)a; p.h[1] = (__bf16)b;
    return p.u;
}

// -------- merged fp32->bf16 converts: z<4 weight transpose, z==4 x --------
// W_q (z==0) pre-scaled by 0.125*log2(e): QK^T emits s*C directly, so the
// attention softmax is a single raw v_exp_f32 (__builtin_amdgcn_exp2f).
__global__ void mha_cvt(const float* __restrict__ x, uint16_t* __restrict__ xb,
                        const float* __restrict__ W0, const float* __restrict__ W1,
                        const float* __restrict__ W2, const float* __restrict__ W3,
                        uint16_t* __restrict__ T0, uint16_t* __restrict__ T1,
                        uint16_t* __restrict__ T2, uint16_t* __restrict__ T3) {
    if (blockIdx.z == 4) {
        int base = (blockIdx.y * 16 + blockIdx.x) * 256 + threadIdx.x;
#pragma unroll
        for (int i = 0; i < 16; ++i) {
            int idx = base + i * 65536;
            float4 f = ((const float4*)x)[idx];
            union { uint16_t u[4]; uint64_t v; } o;
            o.u[0] = f2bf(f.x); o.u[1] = f2bf(f.y); o.u[2] = f2bf(f.z); o.u[3] = f2bf(f.w);
            ((uint64_t*)xb)[idx] = o.v;
        }
        return;
    }
    const float* W; uint16_t* Tt; float sc;
    switch (blockIdx.z) {
        case 0: W = W0; Tt = T0; sc = 0.125f * 1.44269504089f; break;
        case 1: W = W1; Tt = T1; sc = 1.f; break;
        case 2: W = W2; Tt = T2; sc = 1.f; break;
        default: W = W3; Tt = T3; sc = 1.f; break;
    }
    __shared__ float tile[64][65];
    const int c  = threadIdx.x & 63;
    const int r0 = threadIdx.x >> 6;
    const int R0 = blockIdx.y * 64, C0 = blockIdx.x * 64;
#pragma unroll
    for (int rr = 0; rr < 16; ++rr) {
        int r = r0 + rr * 4;
        tile[r][c] = W[(size_t)(R0 + r) * DMODEL + C0 + c];
    }
    __syncthreads();
#pragma unroll
    for (int rr = 0; rr < 16; ++rr) {
        int r = r0 + rr * 4;
        Tt[(size_t)(C0 + r) * DMODEL + R0 + c] = f2bf(tile[c][r] * sc);
    }
}

// ------ bf16 MFMA GEMM, 64M x 128N tile, BK=64, B^T input, swizzled ------
// (R10/R12-proven shape; qkv grid 1536 = 6 blocks/CU @ 24 KB dynamic LDS.
// R5's 128x128 retile was neutral-to-negative -> reverted to this config.)
// Swizzle: row r slot q' holds source sub-chunk q'^(r&7) -> 2-way-only.
// MODE 0: bf16 row-major out. MODE 1: Vt[(b*1024+col)*2048+t] via LDS
// transpose reusing staging smem.
template<int MODE>
__device__ __forceinline__ void gemm_bk64_body(
    const uint16_t* __restrict__ A, const uint16_t* __restrict__ Bt,
    uint16_t* __restrict__ outB) {
    const int K = DMODEL, N = DMODEL;
    extern __shared__ char smem[];                  // 24576 B dynamic
    uint16_t* As = (uint16_t*)smem;                 // [64][64]  8 KB
    uint16_t* Bs = (uint16_t*)(smem + 8192);        // [128][64] 16 KB
    const int tid  = threadIdx.x;
    const int wave = tid >> 6;
    const int lane = tid & 63;
    const int m0 = blockIdx.y * 64;
    const int n0 = blockIdx.x * 128;
    const int lr   = lane & 15;
    const int quad = lane >> 4;

    floatx4 acc[4][2];
#pragma unroll
    for (int i = 0; i < 4; ++i)
#pragma unroll
        for (int j = 0; j < 2; ++j) acc[i][j] = (floatx4)0.0f;

    for (int k0 = 0; k0 < K; k0 += 64) {
#pragma unroll
        for (int i = 0; i < 2; ++i) {               // A: 512 chunks (16B)
            int c = i * 256 + tid;
            int r = c >> 3, s = (c & 7) ^ (r & 7);
            const uint16_t* g = A + (size_t)(m0 + r) * K + k0 + s * 8;
            __builtin_amdgcn_global_load_lds((const __attribute__((address_space(1))) void*)g,
                                             (__attribute__((address_space(3))) void*)(As + (size_t)c * 8), 16, 0, 0);
        }
#pragma unroll
        for (int i = 0; i < 4; ++i) {               // B: 1024 chunks
            int c = i * 256 + tid;
            int r = c >> 3, s = (c & 7) ^ (r & 7);
            const uint16_t* g = Bt + (size_t)(n0 + r) * K + k0 + s * 8;
            __builtin_amdgcn_global_load_lds((const __attribute__((address_space(1))) void*)g,
                                             (__attribute__((address_space(3))) void*)(Bs + (size_t)c * 8), 16, 0, 0);
        }
        __syncthreads();
#pragma unroll
        for (int ks = 0; ks < 2; ++ks) {            // two 32-wide k-halves
            bf16x8 af[4], bfr[2];
#pragma unroll
            for (int mi = 0; mi < 4; ++mi) {
                int row = mi * 16 + lr;
                af[mi] = *(const bf16x8*)&As[row * 64 + (((ks * 4 + quad) ^ (row & 7)) << 3)];
            }
#pragma unroll
            for (int ni = 0; ni < 2; ++ni) {
                int row = wave * 32 + ni * 16 + lr;
                bfr[ni] = *(const bf16x8*)&Bs[row * 64 + (((ks * 4 + quad) ^ (row & 7)) << 3)];
            }
#pragma unroll
            for (int mi = 0; mi < 4; ++mi)
#pragma unroll
                for (int ni = 0; ni < 2; ++ni)
                    acc[mi][ni] = __builtin_amdgcn_mfma_f32_16x16x32_bf16(af[mi], bfr[ni], acc[mi][ni], 0, 0, 0);
        }
        __syncthreads();
    }
    if constexpr (MODE == 1) {
        uint16_t* Ct = (uint16_t*)smem;             // [128][72], 18.4 KB
        const int bb = m0 >> 11, t0 = m0 & 2047;
#pragma unroll
        for (int mi = 0; mi < 4; ++mi)
#pragma unroll
            for (int ni = 0; ni < 2; ++ni) {
                int cl = wave * 32 + ni * 16 + lr;
                int tl = mi * 16 + quad * 4;
                int tls = tl ^ ((cl & 3) << 4);     // 2-way-only bank pattern
                union { uint16_t u[4]; uint64_t v8; } pk;
#pragma unroll
                for (int r = 0; r < 4; ++r) pk.u[r] = f2bf(acc[mi][ni][r]);
                *(uint64_t*)&Ct[cl * 72 + tls] = pk.v8;
            }
        __syncthreads();
#pragma unroll
        for (int k = 0; k < 4; ++k) {
            int c = k * 256 + tid;                  // 1024 chunks of 16B
            int cl = c >> 3, off = (c & 7) * 8;
            int offs = off ^ ((cl & 3) << 4);
            uint4 v = *(const uint4*)&Ct[cl * 72 + offs];
            *(uint4*)&outB[((size_t)(bb * 1024 + n0 + cl)) * 2048 + t0 + off] = v;
        }
    } else {
#pragma unroll
        for (int mi = 0; mi < 4; ++mi)
#pragma unroll
            for (int ni = 0; ni < 2; ++ni) {
                int col = n0 + wave * 32 + ni * 16 + lr;
#pragma unroll
                for (int r = 0; r < 4; ++r) {
                    int row = m0 + mi * 16 + quad * 4 + r;
                    outB[(size_t)row * N + col] = f2bf(acc[mi][ni][r]);
                }
            }
    }
}

__global__ __launch_bounds__(256) void mha_gemm_qkv(
    const uint16_t* __restrict__ A,
    const uint16_t* __restrict__ Wq, const uint16_t* __restrict__ Wk, const uint16_t* __restrict__ Wv,
    uint16_t* __restrict__ Q, uint16_t* __restrict__ K, uint16_t* __restrict__ Vt) {
    switch (blockIdx.z) {
        case 0:  gemm_bk64_body<0>(A, Wq, Q);  break;
        case 1:  gemm_bk64_body<0>(A, Wk, K);  break;
        default: gemm_bk64_body<1>(A, Wv, Vt); break;
    }
}

// ---- out-projection GEMM: 64M x 128N, BK=64, 512 thr / 8 waves ----
// (R14-best config: wave-tile 32x32, grid (8,64) = 2 blocks/CU x 8 waves
// = 16 waves/CU.)
__global__ __launch_bounds__(512) void mha_gemm_out(
    const uint16_t* __restrict__ A, const uint16_t* __restrict__ Wot,
    float* __restrict__ out, const float* __restrict__ bias) {
    const int K = DMODEL, N = DMODEL;
    extern __shared__ char smem[];                  // 24576 B dynamic
    uint16_t* As = (uint16_t*)smem;                 // [64][64]  8 KB
    uint16_t* Bs = (uint16_t*)(smem + 8192);        // [128][64] 16 KB
    const int tid  = threadIdx.x;
    const int wave = tid >> 6;
    const int lane = tid & 63;
    const int m0 = blockIdx.y * 64;
    const int n0 = blockIdx.x * 128;
    const int lr   = lane & 15;
    const int quad = lane >> 4;
    const int wm = wave >> 2, wn = wave & 3;        // 2m x 4n wave grid

    floatx4 acc[2][2];
#pragma unroll
    for (int i = 0; i < 2; ++i)
#pragma unroll
        for (int j = 0; j < 2; ++j) acc[i][j] = (floatx4)0.0f;

    for (int k0 = 0; k0 < K; k0 += 64) {
        {                                           // A: 512 chunks
            int c = tid;
            int r = c >> 3, s = (c & 7) ^ (r & 7);
            const uint16_t* g = A + (size_t)(m0 + r) * K + k0 + s * 8;
            __builtin_amdgcn_global_load_lds((const __attribute__((address_space(1))) void*)g,
                                             (__attribute__((address_space(3))) void*)(As + (size_t)c * 8), 16, 0, 0);
        }
#pragma unroll
        for (int i = 0; i < 2; ++i) {               // B: 1024 chunks
            int c = i * 512 + tid;
            int r = c >> 3, s = (c & 7) ^ (r & 7);
            const uint16_t* g = Wot + (size_t)(n0 + r) * K + k0 + s * 8;
            __builtin_amdgcn_global_load_lds((const __attribute__((address_space(1))) void*)g,
                                             (__attribute__((address_space(3))) void*)(Bs + (size_t)c * 8), 16, 0, 0);
        }
        __syncthreads();
#pragma unroll
        for (int ks = 0; ks < 2; ++ks) {
            bf16x8 af[2], bfr[2];
#pragma unroll
            for (int mi = 0; mi < 2; ++mi) {
                int row = wm * 32 + mi * 16 + lr;
                af[mi] = *(const bf16x8*)&As[row * 64 + (((ks * 4 + quad) ^ (row & 7)) << 3)];
            }
#pragma unroll
            for (int ni = 0; ni < 2; ++ni) {
                int row = wn * 32 + ni * 16 + lr;
                bfr[ni] = *(const bf16x8*)&Bs[row * 64 + (((ks * 4 + quad) ^ (row & 7)) << 3)];
            }
#pragma unroll
            for (int mi = 0; mi < 2; ++mi)
#pragma unroll
                for (int ni = 0; ni < 2; ++ni)
                    acc[mi][ni] = __builtin_amdgcn_mfma_f32_16x16x32_bf16(af[mi], bfr[ni], acc[mi][ni], 0, 0, 0);
        }
        __syncthreads();
    }
#pragma unroll
    for (int mi = 0; mi < 2; ++mi)
#pragma unroll
        for (int ni = 0; ni < 2; ++ni) {
            int col = n0 + wn * 32 + ni * 16 + lr;
            float bv = bias[col];
#pragma unroll
            for (int r = 0; r < 4; ++r) {
                int row = m0 + wm * 32 + mi * 16 + quad * 4 + r;
                out[(size_t)row * N + col] = acc[mi][ni][r] + bv;
            }
        }
}

// ---------------- MFMA flash attention (causal, fixed-base softmax) -------
// R12 = revert to R4-best (168.4 µs measured). Session endpoint rationale:
// attn is pinned at 41.5-46.5 µs across a 10-variant null matrix —
// occupancy x2 (R1), LDS traffic /3 (R2), barrier intervals /2 (R3),
// 16-wave blocks (R8/R9: spill-poisoned at 1024 thr), counted-vmcnt
// depth-2 prefetch (R10: null, consistent with m196 — counted vmcnt
// without fine per-phase interleave doesn't pay), split-kv half-bytes +
// 2 barrier domains (R11: null) — with every pipe <35%. 34.4 GFLOP
// (full-matrix equiv) / 42 µs = ~820 TF-equivalent = the m214-class
// plain-HIP attention floor for a 2-phase schedule. Breaking it needs
// the full co-designed HK T16 dependency graph (8-phase fine interleave
// + reg-staging + stagger), a multi-round rebuild out of session budget.
// Config (R3-form): kv supertile 256, q-tile 128 rows, paired jH=15-p /
// jL=p (p=0..7), TH+TL=9 supertiles; 8 waves = 4 qg(32 rows) x 2
// kvh(128); 32 MFMA 32x32x16 per wave per iter; LDS 128 KB
// double-buffered -> grid 256 = 1 block/CU; in-register softmax
// (swapped QK^T -> exp2 -> cvt_pk -> permlane32_swap); kvh-merge via
// dead LDS buffers; setprio around MFMA clusters.
__global__ __launch_bounds__(512, 2) void mha_attn_mfma(
    const uint16_t* __restrict__ Q, const uint16_t* __restrict__ K,
    const uint16_t* __restrict__ Vt, uint16_t* __restrict__ ctx) {
    extern __shared__ char asmem[];
    uint16_t* Ks0 = (uint16_t*)asmem;              // [2][256*64] 64 KB [kv t][d]
    uint16_t* Vs0 = (uint16_t*)(asmem + 65536);    // [2][64*256] 64 KB [d][kv t]

    const int tid  = threadIdx.x;
    const int wave = tid >> 6;
    const int lane = tid & 63;
    const int l31  = lane & 31;
    const int hi   = lane >> 5;
    const int l7   = lane & 7;
    const int qg   = wave & 3;             // q-row group (32 rows)
    const int kvh  = wave >> 2;            // kv half: [0,128) / [128,256)
    const int h = blockIdx.x;              // head fastest -> XCD locality
    const int p = blockIdx.y;              // 0..7
    const int b = blockIdx.z;
    const int jH = 15 - p, jL = p;         // paired 128-row q-tiles
    const int TH = (17 - p) >> 1;          // 256-wide supertiles; TH+TL=9

    // staging: 8 chunks/thread (4 K + 4 V), XOR source swizzle, linear dest
    const uint16_t* kg[4];
    const uint16_t* vg[4];
    int cch[4];
#pragma unroll
    for (int i = 0; i < 4; ++i) {
        int c = i * 512 + tid; cch[i] = c;        // chunk 0..2047 (16 B)
        int rk = c >> 3, ck = c & 7;              // K: 256 rows x 8 chunks
        kg[i] = K + ((size_t)(b * SEQ_T) + rk) * DMODEL + h * DHEAD + ((ck ^ (rk & 7)) * 8);
        int rv = c >> 5, cv = c & 31;             // V: 64 rows x 32 chunks
        int sv = (cv & 24) | ((cv & 7) ^ (rv & 7));
        vg[i] = Vt + ((size_t)(b * 1024 + h * DHEAD + rv)) * 2048 + sv * 8;
    }

    int q0w = jH * 128 + qg * 32;          // this wave's q base
    bf16x8 qf[4];
    auto load_q = [&]() {
        const uint16_t* qb = Q + ((size_t)(b * SEQ_T) + q0w + l31) * DMODEL + h * DHEAD;
#pragma unroll
        for (int f = 0; f < 4; ++f)
            qf[f] = *(const bf16x8*)(qb + f * 16 + hi * 8);
    };
    load_q();

    floatx16 o[2];
#pragma unroll
    for (int dt = 0; dt < 2; ++dt) o[dt] = (floatx16)0.0f;
    float lac = 0.f;

    auto stage = [&](int kv0, int buf) {   // 8 global_load_lds per thread
        uint16_t* kd = Ks0 + buf * 16384;
        uint16_t* vd = Vs0 + buf * 16384;
#pragma unroll
        for (int i = 0; i < 4; ++i) {
            __builtin_amdgcn_global_load_lds(
                (const __attribute__((address_space(1))) void*)(kg[i] + (size_t)kv0 * DMODEL),
                (__attribute__((address_space(3))) void*)(kd + cch[i] * 8), 16, 0, 0);
            __builtin_amdgcn_global_load_lds(
                (const __attribute__((address_space(1))) void*)(vg[i] + kv0),
                (__attribute__((address_space(3))) void*)(vd + cch[i] * 8), 16, 0, 0);
        }
    };

    // own + partner-half value (lane l <-> l^32) summed
    auto halfsum = [&](float x) -> float {
#if __has_builtin(__builtin_amdgcn_permlane32_swap)
        uint32x2 r = __builtin_amdgcn_permlane32_swap(__float_as_uint(x), __float_as_uint(x), false, false);
        return __uint_as_float(r.x) + __uint_as_float(r.y);
#else
        return x + __shfl_xor(x, 32, 64);
#endif
    };

    // merge kvh=1 partials into kvh=0 (fixed-base softmax => o,l additive).
    // Scratch = dead Ks/Vs[cur] (all reads of them finished at 1st barrier;
    // the in-flight stage targets buf != cur; next DMA into cur is issued
    // only after every wave passes the loop-bottom barrier).
    auto combine_store = [&](int cur) {
        __syncthreads();
        float* osc = (float*)(Vs0 + cur * 16384); // [128 q][64 d] f32, 32 KB
        float* lsc = (float*)(Ks0 + cur * 16384); // 256 f32
        float lt = halfsum(lac);
        if (kvh == 1) {
            if (lane < 32) lsc[qg * 32 + lane] = lt;
#pragma unroll
            for (int dt = 0; dt < 2; ++dt)
#pragma unroll
                for (int r = 0; r < 16; ++r) {
                    int row = (r & 3) + 8 * (r >> 2) + 4 * hi;
                    osc[(qg * 32 + row) * 64 + dt * 32 + l31] = o[dt][r];
                }
        }
        __syncthreads();
        if (kvh == 0) {
            float ltot = lt + lsc[qg * 32 + l31];
            if (lane < 32) lsc[128 + qg * 32 + lane] = 1.f / ltot;
#pragma unroll
            for (int dt = 0; dt < 2; ++dt)
#pragma unroll
                for (int r = 0; r < 16; ++r) {
                    int row = (r & 3) + 8 * (r >> 2) + 4 * hi;
                    float ov = o[dt][r] + osc[(qg * 32 + row) * 64 + dt * 32 + l31];
                    float li = lsc[128 + qg * 32 + row];    // broadcast read
                    size_t addr = ((size_t)(b * SEQ_T) + q0w + row) * DMODEL + h * DHEAD + dt * 32 + l31;
                    ctx[addr] = f2bf(ov * li);
                }
        }
    };

    stage(0, 0);
    __syncthreads();

    for (int t = 0; t < 9; ++t) {
        const int cur = t & 1;
        const int kv0 = (t < TH ? t : t - TH) * 256;
        if (t + 1 < 9) {
            int tn = t + 1;
            stage((tn < TH ? tn : tn - TH) * 256, tn & 1);
        }
        const uint16_t* Kc = Ks0 + cur * 16384;
        const uint16_t* Vc = Vs0 + cur * 16384;
#pragma unroll
        for (int kt = 0; kt < 4; ++kt) {
            const int kb = kv0 + kvh * 128 + kt * 32;
            // QK^T swapped: S^T[k][q] = mfma(K, Q); lane: q = l31, k by reg
            floatx16 s = (floatx16)0.0f;
            __builtin_amdgcn_s_setprio(1);
#pragma unroll
            for (int f = 0; f < 4; ++f) {
                bf16x8 kf = *(const bf16x8*)&Kc[(kvh * 128 + kt * 32 + l31) * 64 + (((2 * f + hi) ^ l7) << 3)];
                s = __builtin_amdgcn_mfma_f32_32x32x16_bf16(kf, qf[f], s, 0, 0, 0);
            }
            __builtin_amdgcn_s_setprio(0);
            if (kb + 31 > q0w) {           // causal mask (covers overhang)
                int qr = q0w + l31;
#pragma unroll
                for (int r = 0; r < 16; ++r) {
                    int k = kb + (r & 3) + 8 * (r >> 2) + 4 * hi;
                    if (k > qr) s[r] = -3e38f;
                }
            }
            // p = exp2(s) (scale folded into W_q); l rides a VALU sum
            float se[16];
#pragma unroll
            for (int r = 0; r < 16; ++r) {
                se[r] = __builtin_amdgcn_exp2f(s[r]);
                lac += se[r];
            }
            // pack pairs; d(m,i) holds k = 8m + 4hi + 2i + {0,1}
            uint32_t d0[2], d1[2], d2[2], d3[2];
#pragma unroll
            for (int i = 0; i < 2; ++i) {
                d0[i] = pack2bf(se[2 * i],      se[2 * i + 1]);
                d1[i] = pack2bf(se[4 + 2 * i],  se[4 + 2 * i + 1]);
                d2[i] = pack2bf(se[8 + 2 * i],  se[8 + 2 * i + 1]);
                d3[i] = pack2bf(se[12 + 2 * i], se[12 + 2 * i + 1]);
            }
            // redistribute across lane halves -> PV A-frags (k contiguous)
            bf16x8 paf[2];
#if __has_builtin(__builtin_amdgcn_permlane32_swap)
            {
                uint32x2 r0 = __builtin_amdgcn_permlane32_swap(d0[0], d1[0], false, false);
                uint32x2 r1 = __builtin_amdgcn_permlane32_swap(d0[1], d1[1], false, false);
                union { uint32_t u[4]; bf16x8 v; } f0;
                f0.u[0] = r0.x; f0.u[1] = r1.x; f0.u[2] = r0.y; f0.u[3] = r1.y;
                paf[0] = f0.v;
                uint32x2 r2 = __builtin_amdgcn_permlane32_swap(d2[0], d3[0], false, false);
                uint32x2 r3 = __builtin_amdgcn_permlane32_swap(d2[1], d3[1], false, false);
                union { uint32_t u[4]; bf16x8 v; } f1;
                f1.u[0] = r2.x; f1.u[1] = r3.x; f1.u[2] = r2.y; f1.u[3] = r3.y;
                paf[1] = f1.v;
            }
#else
            {
                uint32_t s00 = __shfl_xor((int)d0[0], 32, 64), s01 = __shfl_xor((int)d0[1], 32, 64);
                uint32_t s10 = __shfl_xor((int)d1[0], 32, 64), s11 = __shfl_xor((int)d1[1], 32, 64);
                union { uint32_t u[4]; bf16x8 v; } f0;
                f0.u[0] = hi ? s10 : d0[0]; f0.u[1] = hi ? s11 : d0[1];
                f0.u[2] = hi ? d1[0] : s00; f0.u[3] = hi ? d1[1] : s01;
                paf[0] = f0.v;
                uint32_t s20 = __shfl_xor((int)d2[0], 32, 64), s21 = __shfl_xor((int)d2[1], 32, 64);
                uint32_t s30 = __shfl_xor((int)d3[0], 32, 64), s31 = __shfl_xor((int)d3[1], 32, 64);
                union { uint32_t u[4]; bf16x8 v; } f1;
                f1.u[0] = hi ? s30 : d2[0]; f1.u[1] = hi ? s31 : d2[1];
                f1.u[2] = hi ? d3[0] : s20; f1.u[3] = hi ? d3[1] : s21;
                paf[1] = f1.v;
            }
#endif
            // PV: O[q][d] += P x V  (A = in-reg P, B = V^T rows from LDS)
            __builtin_amdgcn_s_setprio(1);
#pragma unroll
            for (int f = 0; f < 2; ++f)
#pragma unroll
                for (int dt = 0; dt < 2; ++dt) {
                    bf16x8 vf = *(const bf16x8*)&Vc[(dt * 32 + l31) * 256 + ((kvh * 16 + ((kt * 4 + 2 * f + hi) ^ l7)) << 3)];
                    o[dt] = __builtin_amdgcn_mfma_f32_32x32x16_bf16(paf[f], vf, o[dt], 0, 0, 0);
                }
            __builtin_amdgcn_s_setprio(0);
        }
        if (t == TH - 1) {                 // high q-tile done: merge + store
            combine_store(cur);
            q0w = jL * 128 + qg * 32;
            load_q();
#pragma unroll
            for (int dt = 0; dt < 2; ++dt) o[dt] = (floatx16)0.0f;
            lac = 0.f;
        }
        if (t + 1 < 9) __syncthreads();    // next buffer staged & landed
    }
    combine_store(0);                      // t=8 -> cur=0
}

extern "C" void kernel_launch(void* const* d_in, const int* in_sizes, int n_in,
                              void* d_out, int out_size, void* d_ws, size_t ws_size,
                              hipStream_t stream) {
    const float* x  = (const float*)d_in[0];
    const float* Wq = (const float*)d_in[1];
    const float* Wk = (const float*)d_in[2];
    const float* Wv = (const float*)d_in[3];
    const float* Wo = (const float*)d_in[4];
    const float* bo = (const float*)d_in[5];
    float* out = (float*)d_out;

    char* ws = (char*)d_ws;
    const size_t SZ_X = (size_t)4096 * DMODEL * 2;   // 8 MB
    const size_t SZ_W = (size_t)DMODEL * DMODEL * 2; // 2 MB
    size_t off = 0;
    uint16_t* xb  = (uint16_t*)(ws + off); off += SZ_X;
    uint16_t* wqt = (uint16_t*)(ws + off); off += SZ_W;
    uint16_t* wkt = (uint16_t*)(ws + off); off += SZ_W;
    uint16_t* wvt = (uint16_t*)(ws + off); off += SZ_W;
    uint16_t* wot = (uint16_t*)(ws + off); off += SZ_W;
    uint16_t* Qb  = (uint16_t*)(ws + off); off += SZ_X;
    uint16_t* Kb  = (uint16_t*)(ws + off); off += SZ_X;
    uint16_t* Vtb = (uint16_t*)(ws + off); off += SZ_X;  // per-head transposed V
    uint16_t* Cb  = (uint16_t*)(ws + off); off += SZ_X;
    (void)ws_size; (void)in_sizes; (void)n_in; (void)out_size;

    mha_cvt<<<dim3(16, 16, 5), 256, 0, stream>>>(x, xb, Wq, Wk, Wv, Wo, wqt, wkt, wvt, wot);
    mha_gemm_qkv<<<dim3(8, 64, 3), 256, 24576, stream>>>(xb, wqt, wkt, wvt, Qb, Kb, Vtb);
    mha_attn_mfma<<<dim3(NHEAD, 8, 2), 512, 131072, stream>>>(Qb, Kb, Vtb, Cb);
    mha_gemm_out<<<dim3(8, 64), 512, 24576, stream>>>(Cb, wot, out, bo);
}